// Round 10
// baseline (379.676 us; speedup 1.0000x reference)
//
#include <hip/hip_runtime.h>
#include <hip/hip_bf16.h>
#include <math.h>

using bf16 = __hip_bfloat16;
typedef __attribute__((ext_vector_type(8))) short short8;
typedef __attribute__((ext_vector_type(4))) float float4v;

template <typename T> __device__ inline T cvt_out(float v);
template <> __device__ inline float cvt_out<float>(float v) { return v; }
template <> __device__ inline bf16 cvt_out<bf16>(float v) { return __float2bfloat16(v); }

__device__ inline void gload_lds16(const bf16* g, bf16* l) {
    __builtin_amdgcn_global_load_lds(
        (const __attribute__((address_space(1))) void*)g,
        (__attribute__((address_space(3))) void*)l, 16, 0, 0);
}

// ---- fused fp32->bf16 convert for x + 6 weights, one launch ----
struct CvtPack {
    const float* src[7];
    bf16* dst[7];
    int end[7];   // cumulative element ends
};

__global__ __launch_bounds__(256) void cvt_all(CvtPack p) {
    int e = (blockIdx.x * 256 + threadIdx.x) * 4;
    int start = 0;
#pragma unroll
    for (int s = 0; s < 7; ++s) {
        if (e < p.end[s]) {
            int off = e - start;
            float4 v = *(const float4*)(p.src[s] + off);
            bf16* d = p.dst[s] + off;
            d[0] = __float2bfloat16(v.x);
            d[1] = __float2bfloat16(v.y);
            d[2] = __float2bfloat16(v.z);
            d[3] = __float2bfloat16(v.w);
            return;
        }
        start = p.end[s];
    }
}

// ---- split-K reduce: out = act( sum_k p[k*mn+..] + bias ) ----
__device__ inline float4 load4f(const float* p) { return *(const float4*)p; }
__device__ inline float4 load4f(const bf16* p) {
    ushort4 u = *(const ushort4*)p;
    float4 r;
    r.x = __uint_as_float((unsigned)u.x << 16);
    r.y = __uint_as_float((unsigned)u.y << 16);
    r.z = __uint_as_float((unsigned)u.z << 16);
    r.w = __uint_as_float((unsigned)u.w << 16);
    return r;
}
__device__ inline void store4(float* p, float4 v) { *(float4*)p = v; }
__device__ inline void store4(bf16* p, float4 v) {
    p[0] = __float2bfloat16(v.x); p[1] = __float2bfloat16(v.y);
    p[2] = __float2bfloat16(v.z); p[3] = __float2bfloat16(v.w);
}

template <int NK, int ACT, typename InT, typename OutT>
__global__ __launch_bounds__(256) void reduceK(const InT* __restrict__ p,
                                               const float* __restrict__ bias,
                                               OutT* __restrict__ out,
                                               size_t mn, int nmask, int total4) {
    int i = blockIdx.x * 256 + threadIdx.x;
    if (i < total4) {
        int idx = i * 4;
        float4 r = *(const float4*)(bias + (idx & nmask));
#pragma unroll
        for (int k = 0; k < NK; ++k) {
            float4 a = load4f(p + k * mn + idx);
            r.x += a.x; r.y += a.y; r.z += a.z; r.w += a.w;
        }
        if (ACT == 1) {
            r.x = fmaxf(r.x, 0.f); r.y = fmaxf(r.y, 0.f);
            r.z = fmaxf(r.z, 0.f); r.w = fmaxf(r.w, 0.f);
        } else if (ACT == 2) {
            r.x = tanhf(r.x); r.y = tanhf(r.y);
            r.z = tanhf(r.z); r.w = tanhf(r.w);
        }
        store4(out + idx, r);
    }
}

// ---- 256-thread GEMM: tile (32*WMT)x(32*WNT), 4 waves 2x2, direct stores ----
// C[m][n] = act( sum_k A[m][k]*W[n][k] + bias[n] ); XCD swizzle on 1D grid.
// PARTIAL: split-K, blockIdx.y -> chunk, raw partial (no bias/act) at C + y*M*N.
template <int ACT, typename OutT, int WMT, int WNT, int BKT, bool PARTIAL>
__global__ __launch_bounds__(256) void gemm_bt(const bf16* __restrict__ A,
                                               const bf16* __restrict__ W,
                                               const float* __restrict__ bias,
                                               OutT* __restrict__ C,
                                               int M, int N, int K,
                                               int nbn, int kcount) {
    constexpr int TBM = 32 * WMT;
    constexpr int TBN = 32 * WNT;
    constexpr int CPR = BKT / 8;
    constexpr int CA = TBM * CPR;
    constexpr int CB = TBN * CPR;

    __shared__ bf16 As[TBM * BKT];
    __shared__ bf16 Bs[TBN * BKT];

    const int bi = blockIdx.x;
    const int xcd = bi & 7, t = bi >> 3;
    const int bn = t % nbn;
    const int bm = xcd + 8 * (t / nbn);
    const int kbeg = PARTIAL ? blockIdx.y * kcount : 0;
    OutT* Cp = PARTIAL ? C + (size_t)blockIdx.y * M * N : C;

    const int tid = threadIdx.x;
    const int wave = tid >> 6, lane = tid & 63;
    const int wm = (wave >> 1) * (16 * WMT), wn = (wave & 1) * (16 * WNT);
    const int quad = lane >> 4, lrow = lane & 15;

    float4v acc[WMT][WNT] = {};
    const size_t arow = (size_t)(bm * TBM) * K;
    const size_t brow = (size_t)(bn * TBN) * K;

    for (int k0 = kbeg; k0 < kbeg + kcount; k0 += BKT) {
        __syncthreads();
#pragma unroll
        for (int tt = 0; tt < CA / 256; ++tt) {
            int base = tt * 256 + wave * 64;       // wave-uniform
            int c = base + lane;
            int row = c / CPR, col = (c % CPR) * 8;
            gload_lds16(A + arow + (size_t)row * K + k0 + col, As + base * 8);
        }
#pragma unroll
        for (int tt = 0; tt < CB / 256; ++tt) {
            int base = tt * 256 + wave * 64;
            int c = base + lane;
            int row = c / CPR, col = (c % CPR) * 8;
            gload_lds16(W + brow + (size_t)row * K + k0 + col, Bs + base * 8);
        }
        __syncthreads();
#pragma unroll
        for (int kk = 0; kk < BKT; kk += 32) {
            short8 af[WMT], bfr[WNT];
#pragma unroll
            for (int i = 0; i < WMT; ++i)
                af[i] = *(const short8*)(As + (wm + i * 16 + lrow) * BKT + kk + quad * 8);
#pragma unroll
            for (int j = 0; j < WNT; ++j)
                bfr[j] = *(const short8*)(Bs + (wn + j * 16 + lrow) * BKT + kk + quad * 8);
#pragma unroll
            for (int i = 0; i < WMT; ++i)
#pragma unroll
                for (int j = 0; j < WNT; ++j)
                    acc[i][j] = __builtin_amdgcn_mfma_f32_16x16x32_bf16(af[i], bfr[j], acc[i][j], 0, 0, 0);
        }
    }

    // direct-store epilogue; C/D layout col=lane&15, row=quad*4+reg
#pragma unroll
    for (int i = 0; i < WMT; ++i) {
        int m0 = bm * TBM + wm + i * 16 + quad * 4;
#pragma unroll
        for (int j = 0; j < WNT; ++j) {
            int n = bn * TBN + wn + j * 16 + lrow;
            if constexpr (PARTIAL) {
#pragma unroll
                for (int r = 0; r < 4; ++r)
                    Cp[(size_t)(m0 + r) * N + n] = cvt_out<OutT>(acc[i][j][r]);
            } else {
                float bv = bias[n];
#pragma unroll
                for (int r = 0; r < 4; ++r) {
                    float v = acc[i][j][r] + bv;
                    if (ACT == 1) v = fmaxf(v, 0.f);
                    else if (ACT == 2) v = tanhf(v);
                    Cp[(size_t)(m0 + r) * N + n] = cvt_out<OutT>(v);
                }
            }
        }
    }
}

// ---- 512-thread GEMM: tile 256x128, 8 waves 4x2, per-wave 64x64 ----
template <int ACT, typename OutT>
__global__ __launch_bounds__(512, 4) void gemm_bt_wide(const bf16* __restrict__ A,
                                                       const bf16* __restrict__ W,
                                                       const float* __restrict__ bias,
                                                       OutT* __restrict__ C,
                                                       int M, int N, int K,
                                                       int nbn) {
    constexpr int TBM = 256, TBN = 128, BKT = 64;
    constexpr int CPR = BKT / 8;
    constexpr int CA = TBM * CPR;         // 2048
    constexpr int CB = TBN * CPR;         // 1024

    __shared__ bf16 As[TBM * BKT];        // 32 KB
    __shared__ bf16 Bs[TBN * BKT];        // 16 KB

    const int bi = blockIdx.x;
    const int xcd = bi & 7, t = bi >> 3;
    const int bn = t % nbn;
    const int bm = xcd + 8 * (t / nbn);

    const int tid = threadIdx.x;
    const int wave = tid >> 6, lane = tid & 63;
    const int wm = (wave >> 1) * 64, wn = (wave & 1) * 64;
    const int quad = lane >> 4, lrow = lane & 15;

    float4v acc[4][4] = {};
    const size_t arow = (size_t)(bm * TBM) * K;
    const size_t brow = (size_t)(bn * TBN) * K;

    for (int k0 = 0; k0 < K; k0 += BKT) {
        __syncthreads();
#pragma unroll
        for (int tt = 0; tt < CA / 512; ++tt) {
            int base = tt * 512 + wave * 64;
            int c = base + lane;
            int row = c / CPR, col = (c % CPR) * 8;
            gload_lds16(A + arow + (size_t)row * K + k0 + col, As + base * 8);
        }
#pragma unroll
        for (int tt = 0; tt < CB / 512; ++tt) {
            int base = tt * 512 + wave * 64;
            int c = base + lane;
            int row = c / CPR, col = (c % CPR) * 8;
            gload_lds16(W + brow + (size_t)row * K + k0 + col, Bs + base * 8);
        }
        __syncthreads();
#pragma unroll
        for (int kk = 0; kk < BKT; kk += 32) {
            short8 af[4], bfr[4];
#pragma unroll
            for (int i = 0; i < 4; ++i)
                af[i] = *(const short8*)(As + (wm + i * 16 + lrow) * BKT + kk + quad * 8);
#pragma unroll
            for (int j = 0; j < 4; ++j)
                bfr[j] = *(const short8*)(Bs + (wn + j * 16 + lrow) * BKT + kk + quad * 8);
#pragma unroll
            for (int i = 0; i < 4; ++i)
#pragma unroll
                for (int j = 0; j < 4; ++j)
                    acc[i][j] = __builtin_amdgcn_mfma_f32_16x16x32_bf16(af[i], bfr[j], acc[i][j], 0, 0, 0);
        }
    }

#pragma unroll
    for (int i = 0; i < 4; ++i) {
        int m0 = bm * TBM + wm + i * 16 + quad * 4;
#pragma unroll
        for (int j = 0; j < 4; ++j) {
            int n = bn * TBN + wn + j * 16 + lrow;
            float bv = bias[n];
#pragma unroll
            for (int r = 0; r < 4; ++r) {
                float v = acc[i][j][r] + bv;
                if (ACT == 1) v = fmaxf(v, 0.f);
                else if (ACT == 2) v = tanhf(v);
                C[(size_t)(m0 + r) * N + n] = cvt_out<OutT>(v);
            }
        }
    }
}

// One wave per row: power-norm -> single-tap channel + noise -> LS h_est -> ZF.
__global__ __launch_bounds__(64) void channel_kernel(const float* __restrict__ s,
                                                     const float* __restrict__ h,
                                                     const float* __restrict__ noise,
                                                     float* __restrict__ xr_f,
                                                     bf16* __restrict__ xr_b) {
    const int b = blockIdx.x, lane = threadIdx.x;
    const float* srow = s + (size_t)b * 256;

    float ss = 0.f;
#pragma unroll
    for (int t = 0; t < 4; ++t) {
        float v = srow[lane + 64 * t];
        ss += v * v;
    }
#pragma unroll
    for (int off = 32; off; off >>= 1) ss += __shfl_xor(ss, off);
    const float inv = sqrtf(128.0f) / sqrtf(ss);

    const float hre = h[0], him = h[1];

    float yre[2], yim[2];
    float nre = 0.f, nim = 0.f, den = 0.f;
#pragma unroll
    for (int t = 0; t < 2; ++t) {
        int c = lane + 64 * t;
        float tr = srow[2 * c] * inv, ti = srow[2 * c + 1] * inv;
        float yr = hre * tr - him * ti + noise[(size_t)b * 256 + 2 * c];
        float yi = hre * ti + him * tr + noise[(size_t)b * 256 + 2 * c + 1];
        yre[t] = yr; yim[t] = yi;
        nre += yr * tr + yi * ti;
        nim += yi * tr - yr * ti;
        den += tr * tr + ti * ti;
    }
#pragma unroll
    for (int off = 32; off; off >>= 1) {
        nre += __shfl_xor(nre, off);
        nim += __shfl_xor(nim, off);
        den += __shfl_xor(den, off);
    }
    const float her = nre / den, hei = nim / den;
    const float d2 = her * her + hei * hei + 1e-12f;

#pragma unroll
    for (int t = 0; t < 2; ++t) {
        int c = lane + 64 * t;
        float xre = (yre[t] * her + yim[t] * hei) / d2;
        float xim = (yim[t] * her - yre[t] * hei) / d2;
        xr_f[(size_t)b * 256 + 2 * c] = xre;
        xr_f[(size_t)b * 256 + 2 * c + 1] = xim;
        xr_b[(size_t)b * 256 + 2 * c] = __float2bfloat16(xre);
        xr_b[(size_t)b * 256 + 2 * c + 1] = __float2bfloat16(xim);
    }
}

// One wave per row: h_inv = g2 @ w_rtn3^T + b_rtn3 (N=6), 3-tap complex FIR.
__global__ __launch_bounds__(64) void rtn_taps_conv(const bf16* __restrict__ g2,
                                                    const float* __restrict__ wr3,
                                                    const float* __restrict__ br3,
                                                    const float* __restrict__ xr_f,
                                                    bf16* __restrict__ xr2) {
    const int b = blockIdx.x, lane = threadIdx.x;
    const bf16* grow = g2 + (size_t)b * 1024;

    float acc[6] = {0.f, 0.f, 0.f, 0.f, 0.f, 0.f};
#pragma unroll
    for (int t = 0; t < 16; ++t) {
        int k = lane + 64 * t;
        float gv = __bfloat162float(grow[k]);
#pragma unroll
        for (int j = 0; j < 6; ++j) acc[j] += gv * wr3[j * 1024 + k];
    }
#pragma unroll
    for (int j = 0; j < 6; ++j)
#pragma unroll
        for (int off = 32; off; off >>= 1) acc[j] += __shfl_xor(acc[j], off);

    float tre[3], tim[3];
#pragma unroll
    for (int l = 0; l < 3; ++l) {
        tre[l] = acc[2 * l] + br3[2 * l];
        tim[l] = acc[2 * l + 1] + br3[2 * l + 1];
    }

    const float* xrow = xr_f + (size_t)b * 256;
#pragma unroll
    for (int t = 0; t < 2; ++t) {
        int c = lane + 64 * t;
        float ore = 0.f, oim = 0.f;
#pragma unroll
        for (int l = 0; l < 3; ++l) {
            int cc = c - l;
            if (cc >= 0) {
                float xre = xrow[2 * cc], xim = xrow[2 * cc + 1];
                ore += tre[l] * xre - tim[l] * xim;
                oim += tre[l] * xim + tim[l] * xre;
            }
        }
        xr2[(size_t)b * 256 + 2 * c] = __float2bfloat16(ore);
        xr2[(size_t)b * 256 + 2 * c + 1] = __float2bfloat16(oim);
    }
}

extern "C" void kernel_launch(void* const* d_in, const int* in_sizes, int n_in,
                              void* d_out, int out_size, void* d_ws, size_t ws_size,
                              hipStream_t stream) {
    constexpr int B = 8192, D_IN = 512, H1 = 4096, CH = 256, HR = 1024, H2 = 4096, DOUT = 512;

    const float* x   = (const float*)d_in[0];
    const float* w1  = (const float*)d_in[1];
    const float* b1  = (const float*)d_in[2];
    const float* w2  = (const float*)d_in[3];
    const float* b2  = (const float*)d_in[4];
    const float* wr1 = (const float*)d_in[5];
    const float* br1 = (const float*)d_in[6];
    const float* wr2 = (const float*)d_in[7];
    const float* br2 = (const float*)d_in[8];
    const float* wr3 = (const float*)d_in[9];
    const float* br3 = (const float*)d_in[10];
    const float* w3  = (const float*)d_in[11];
    const float* b3  = (const float*)d_in[12];
    const float* w4  = (const float*)d_in[13];
    const float* b4  = (const float*)d_in[14];
    const float* h   = (const float*)d_in[15];
    const float* noise = (const float*)d_in[16];

    // ---- workspace layout (bytes), peak 115.9 MB; liveness traced per launch ----
    char* ws = (char*)d_ws;
    bf16*  a    = (bf16*)(ws + 0);          // 64 MB: G1 out, G2 in; dead after G2
    float* sF   = (float*)(ws + 0);         // 8 MB: reduce(G2) out, channel in (a dead)
    bf16*  g1   = (bf16*)(ws + 0);          // 16 MB: G3 out (sF dead post-channel)
    bf16*  g2   = (bf16*)(ws + 16777216);   // 16 MB: reduce(G4) out, rtn in
    bf16*  g4P  = (bf16*)(ws + 33554432);   // 2 x 16 MB: G4 bf16 partials (33..67 MB dead at G4)
    bf16*  tbuf = (bf16*)(ws + 0);          // 64 MB: G5 out (g1/g2 dead post-rtn)
    bf16*  w1B  = (bf16*)(ws + 67108864);   // 4 MB
    bf16*  w2B  = (bf16*)(ws + 71303168);   // 2 MB
    bf16*  wr1B = (bf16*)(ws + 73400320);   // 0.5 MB
    bf16*  wr2B = (bf16*)(ws + 73924608);   // 2 MB
    bf16*  w3B  = (bf16*)(ws + 76021760);   // 2 MB
    bf16*  w4B  = (bf16*)(ws + 78118912);   // 4 MB
    bf16*  xB   = (bf16*)(ws + 82313216);   // 8 MB: bf16(x), dead after G1
    bf16*  g2P  = (bf16*)(ws + 82313216);   // 8 x 4 MB: G2 bf16 partials (82..116 MB dead at G2)
    float* xrF  = (float*)(ws + 99090432);  // 8 MB: channel out, rtn in (G2 partials dead)
    bf16*  xrB  = (bf16*)(ws + 107479040);  // 4 MB: channel out, G3 in
    bf16*  xr2  = (bf16*)(ws + 111673344);  // 4 MB: rtn out, G5 in
    bf16*  g6P  = (bf16*)(ws + 82313216);   // 4 x 8 MB: G6 partials (xrF/xrB/xr2 dead at G6)

    dim3 blk(256);

    // ---- single fused fp32->bf16 convert ----
    CvtPack p;
    const float* srcs[7] = {x, w1, w2, wr1, wr2, w3, w4};
    bf16* dsts[7] = {xB, w1B, w2B, wr1B, wr2B, w3B, w4B};
    int ns[7] = {B * D_IN, H1 * D_IN, CH * H1, HR * CH, HR * HR, H2 * CH, DOUT * H2};
    int cum = 0;
    for (int i = 0; i < 7; ++i) { p.src[i] = srcs[i]; p.dst[i] = dsts[i]; cum += ns[i]; p.end[i] = cum; }
    cvt_all<<<(cum / 4 + 255) / 256, blk, 0, stream>>>(p);

    // ---- encoder ----
    // G1: 256x128 wide, nbm=32, nbn=32, grid 1024 x 512thr
    gemm_bt_wide<1, bf16><<<32 * 32, dim3(512), 0, stream>>>(
        xB, w1B, b1, a, B, H1, D_IN, 32);
    // G2: 128x128, split-K=8 (kc=512), nbn=2, grid (128,8)=1024 (4/CU), bf16 partials
    gemm_bt<0, bf16, 4, 4, 64, true><<<dim3(64 * 2, 8), blk, 0, stream>>>(
        a, w2B, nullptr, g2P, B, CH, H1, 2, H1 / 8);
    reduceK<8, 0, bf16, float><<<(B * CH / 4 + 255) / 256, blk, 0, stream>>>(
        g2P, b2, sF, (size_t)B * CH, CH - 1, B * CH / 4);
    // ---- channel + ZF (fp32) ----
    channel_kernel<<<B, 64, 0, stream>>>(sF, h, noise, xrF, xrB);
    // ---- RTN ----
    // G3: 128x64, nbm=64, nbn=16, grid 1024
    gemm_bt<2, bf16, 4, 2, 64, false><<<64 * 16, blk, 0, stream>>>(
        xrB, wr1B, br1, g1, B, HR, CH, 16, CH);
    // G4: 128x128, split-K=2 (kc=512), nbn=8, grid (512,2)=1024, bf16 partials;
    // tanh+bias applied in the reduce
    gemm_bt<0, bf16, 4, 4, 64, true><<<dim3(64 * 8, 2), blk, 0, stream>>>(
        g1, wr2B, nullptr, g4P, B, HR, HR, 8, HR / 2);
    reduceK<2, 2, bf16, bf16><<<(B * HR / 4 + 255) / 256, blk, 0, stream>>>(
        g4P, br2, g2, (size_t)B * HR, HR - 1, B * HR / 4);
    rtn_taps_conv<<<B, 64, 0, stream>>>(g2, wr3, br3, xrF, xr2);
    // ---- decoder ----
    // G5: 256x128 wide, nbm=32, nbn=32, grid 1024 x 512thr
    gemm_bt_wide<1, bf16><<<32 * 32, dim3(512), 0, stream>>>(
        xr2, w3B, b3, tbuf, B, H2, CH, 32);
    // G6: 128x128, split-K=4 (kc=1024), nbn=4, grid (256,4)=1024, bf16 partials
    gemm_bt<0, bf16, 4, 4, 64, true><<<dim3(64 * 4, 4), blk, 0, stream>>>(
        tbuf, w4B, nullptr, g6P, B, DOUT, H2, 4, H2 / 4);
    reduceK<4, 0, bf16, float><<<(B * DOUT / 4 + 255) / 256, blk, 0, stream>>>(
        g6P, b4, (float*)d_out, (size_t)B * DOUT, DOUT - 1, B * DOUT / 4);
}

// Round 11
// 366.755 us; speedup vs baseline: 1.0352x; 1.0352x over previous
//
#include <hip/hip_runtime.h>
#include <hip/hip_bf16.h>
#include <math.h>

using bf16 = __hip_bfloat16;
typedef __attribute__((ext_vector_type(8))) short short8;
typedef __attribute__((ext_vector_type(4))) float float4v;

template <typename T> __device__ inline T cvt_out(float v);
template <> __device__ inline float cvt_out<float>(float v) { return v; }
template <> __device__ inline bf16 cvt_out<bf16>(float v) { return __float2bfloat16(v); }

__device__ inline void gload_lds16(const bf16* g, bf16* l) {
    __builtin_amdgcn_global_load_lds(
        (const __attribute__((address_space(1))) void*)g,
        (__attribute__((address_space(3))) void*)l, 16, 0, 0);
}

// ---- fused fp32->bf16 convert for x + 6 weights, one launch ----
struct CvtPack {
    const float* src[7];
    bf16* dst[7];
    int end[7];   // cumulative element ends
};

__global__ __launch_bounds__(256) void cvt_all(CvtPack p) {
    int e = (blockIdx.x * 256 + threadIdx.x) * 4;
    int start = 0;
#pragma unroll
    for (int s = 0; s < 7; ++s) {
        if (e < p.end[s]) {
            int off = e - start;
            float4 v = *(const float4*)(p.src[s] + off);
            bf16* d = p.dst[s] + off;
            d[0] = __float2bfloat16(v.x);
            d[1] = __float2bfloat16(v.y);
            d[2] = __float2bfloat16(v.z);
            d[3] = __float2bfloat16(v.w);
            return;
        }
        start = p.end[s];
    }
}

// ---- split-K reduce: out = act( sum_k p[k*mn+..] + bias ) ----
__device__ inline float4 load4f(const float* p) { return *(const float4*)p; }
__device__ inline float4 load4f(const bf16* p) {
    ushort4 u = *(const ushort4*)p;
    float4 r;
    r.x = __uint_as_float((unsigned)u.x << 16);
    r.y = __uint_as_float((unsigned)u.y << 16);
    r.z = __uint_as_float((unsigned)u.z << 16);
    r.w = __uint_as_float((unsigned)u.w << 16);
    return r;
}
__device__ inline void store4(float* p, float4 v) { *(float4*)p = v; }
__device__ inline void store4(bf16* p, float4 v) {
    p[0] = __float2bfloat16(v.x); p[1] = __float2bfloat16(v.y);
    p[2] = __float2bfloat16(v.z); p[3] = __float2bfloat16(v.w);
}

template <int NK, int ACT, typename InT, typename OutT>
__global__ __launch_bounds__(256) void reduceK(const InT* __restrict__ p,
                                               const float* __restrict__ bias,
                                               OutT* __restrict__ out,
                                               size_t mn, int nmask, int total4) {
    int i = blockIdx.x * 256 + threadIdx.x;
    if (i < total4) {
        int idx = i * 4;
        float4 r = *(const float4*)(bias + (idx & nmask));
#pragma unroll
        for (int k = 0; k < NK; ++k) {
            float4 a = load4f(p + k * mn + idx);
            r.x += a.x; r.y += a.y; r.z += a.z; r.w += a.w;
        }
        if (ACT == 1) {
            r.x = fmaxf(r.x, 0.f); r.y = fmaxf(r.y, 0.f);
            r.z = fmaxf(r.z, 0.f); r.w = fmaxf(r.w, 0.f);
        } else if (ACT == 2) {
            r.x = tanhf(r.x); r.y = tanhf(r.y);
            r.z = tanhf(r.z); r.w = tanhf(r.w);
        }
        store4(out + idx, r);
    }
}

// ---- 256-thread GEMM: tile (32*WMT)x(32*WNT), 4 waves 2x2, direct stores ----
// C[m][n] = act( sum_k A[m][k]*W[n][k] + bias[n] ); XCD swizzle on 1D grid.
// PARTIAL: split-K, blockIdx.y -> chunk, raw partial (no bias/act) at C + y*M*N.
template <int ACT, typename OutT, int WMT, int WNT, int BKT, bool PARTIAL>
__global__ __launch_bounds__(256) void gemm_bt(const bf16* __restrict__ A,
                                               const bf16* __restrict__ W,
                                               const float* __restrict__ bias,
                                               OutT* __restrict__ C,
                                               int M, int N, int K,
                                               int nbn, int kcount) {
    constexpr int TBM = 32 * WMT;
    constexpr int TBN = 32 * WNT;
    constexpr int CPR = BKT / 8;
    constexpr int CA = TBM * CPR;
    constexpr int CB = TBN * CPR;

    __shared__ bf16 As[TBM * BKT];
    __shared__ bf16 Bs[TBN * BKT];

    const int bi = blockIdx.x;
    const int xcd = bi & 7, t = bi >> 3;
    const int bn = t % nbn;
    const int bm = xcd + 8 * (t / nbn);
    const int kbeg = PARTIAL ? blockIdx.y * kcount : 0;
    OutT* Cp = PARTIAL ? C + (size_t)blockIdx.y * M * N : C;

    const int tid = threadIdx.x;
    const int wave = tid >> 6, lane = tid & 63;
    const int wm = (wave >> 1) * (16 * WMT), wn = (wave & 1) * (16 * WNT);
    const int quad = lane >> 4, lrow = lane & 15;

    float4v acc[WMT][WNT] = {};
    const size_t arow = (size_t)(bm * TBM) * K;
    const size_t brow = (size_t)(bn * TBN) * K;

    for (int k0 = kbeg; k0 < kbeg + kcount; k0 += BKT) {
        __syncthreads();
#pragma unroll
        for (int tt = 0; tt < CA / 256; ++tt) {
            int base = tt * 256 + wave * 64;       // wave-uniform
            int c = base + lane;
            int row = c / CPR, col = (c % CPR) * 8;
            gload_lds16(A + arow + (size_t)row * K + k0 + col, As + base * 8);
        }
#pragma unroll
        for (int tt = 0; tt < CB / 256; ++tt) {
            int base = tt * 256 + wave * 64;
            int c = base + lane;
            int row = c / CPR, col = (c % CPR) * 8;
            gload_lds16(W + brow + (size_t)row * K + k0 + col, Bs + base * 8);
        }
        __syncthreads();
#pragma unroll
        for (int kk = 0; kk < BKT; kk += 32) {
            short8 af[WMT], bfr[WNT];
#pragma unroll
            for (int i = 0; i < WMT; ++i)
                af[i] = *(const short8*)(As + (wm + i * 16 + lrow) * BKT + kk + quad * 8);
#pragma unroll
            for (int j = 0; j < WNT; ++j)
                bfr[j] = *(const short8*)(Bs + (wn + j * 16 + lrow) * BKT + kk + quad * 8);
#pragma unroll
            for (int i = 0; i < WMT; ++i)
#pragma unroll
                for (int j = 0; j < WNT; ++j)
                    acc[i][j] = __builtin_amdgcn_mfma_f32_16x16x32_bf16(af[i], bfr[j], acc[i][j], 0, 0, 0);
        }
    }

    // direct-store epilogue; C/D layout col=lane&15, row=quad*4+reg
#pragma unroll
    for (int i = 0; i < WMT; ++i) {
        int m0 = bm * TBM + wm + i * 16 + quad * 4;
#pragma unroll
        for (int j = 0; j < WNT; ++j) {
            int n = bn * TBN + wn + j * 16 + lrow;
            if constexpr (PARTIAL) {
#pragma unroll
                for (int r = 0; r < 4; ++r)
                    Cp[(size_t)(m0 + r) * N + n] = cvt_out<OutT>(acc[i][j][r]);
            } else {
                float bv = bias[n];
#pragma unroll
                for (int r = 0; r < 4; ++r) {
                    float v = acc[i][j][r] + bv;
                    if (ACT == 1) v = fmaxf(v, 0.f);
                    else if (ACT == 2) v = tanhf(v);
                    Cp[(size_t)(m0 + r) * N + n] = cvt_out<OutT>(v);
                }
            }
        }
    }
}

// ---- 512-thread GEMM: tile 256x128, 8 waves 4x2, per-wave 64x64 ----
template <int ACT, typename OutT>
__global__ __launch_bounds__(512, 4) void gemm_bt_wide(const bf16* __restrict__ A,
                                                       const bf16* __restrict__ W,
                                                       const float* __restrict__ bias,
                                                       OutT* __restrict__ C,
                                                       int M, int N, int K,
                                                       int nbn) {
    constexpr int TBM = 256, TBN = 128, BKT = 64;
    constexpr int CPR = BKT / 8;
    constexpr int CA = TBM * CPR;         // 2048
    constexpr int CB = TBN * CPR;         // 1024

    __shared__ bf16 As[TBM * BKT];        // 32 KB
    __shared__ bf16 Bs[TBN * BKT];        // 16 KB

    const int bi = blockIdx.x;
    const int xcd = bi & 7, t = bi >> 3;
    const int bn = t % nbn;
    const int bm = xcd + 8 * (t / nbn);

    const int tid = threadIdx.x;
    const int wave = tid >> 6, lane = tid & 63;
    const int wm = (wave >> 1) * 64, wn = (wave & 1) * 64;
    const int quad = lane >> 4, lrow = lane & 15;

    float4v acc[4][4] = {};
    const size_t arow = (size_t)(bm * TBM) * K;
    const size_t brow = (size_t)(bn * TBN) * K;

    for (int k0 = 0; k0 < K; k0 += BKT) {
        __syncthreads();
#pragma unroll
        for (int tt = 0; tt < CA / 512; ++tt) {
            int base = tt * 512 + wave * 64;
            int c = base + lane;
            int row = c / CPR, col = (c % CPR) * 8;
            gload_lds16(A + arow + (size_t)row * K + k0 + col, As + base * 8);
        }
#pragma unroll
        for (int tt = 0; tt < CB / 512; ++tt) {
            int base = tt * 512 + wave * 64;
            int c = base + lane;
            int row = c / CPR, col = (c % CPR) * 8;
            gload_lds16(W + brow + (size_t)row * K + k0 + col, Bs + base * 8);
        }
        __syncthreads();
#pragma unroll
        for (int kk = 0; kk < BKT; kk += 32) {
            short8 af[4], bfr[4];
#pragma unroll
            for (int i = 0; i < 4; ++i)
                af[i] = *(const short8*)(As + (wm + i * 16 + lrow) * BKT + kk + quad * 8);
#pragma unroll
            for (int j = 0; j < 4; ++j)
                bfr[j] = *(const short8*)(Bs + (wn + j * 16 + lrow) * BKT + kk + quad * 8);
#pragma unroll
            for (int i = 0; i < 4; ++i)
#pragma unroll
                for (int j = 0; j < 4; ++j)
                    acc[i][j] = __builtin_amdgcn_mfma_f32_16x16x32_bf16(af[i], bfr[j], acc[i][j], 0, 0, 0);
        }
    }

#pragma unroll
    for (int i = 0; i < 4; ++i) {
        int m0 = bm * TBM + wm + i * 16 + quad * 4;
#pragma unroll
        for (int j = 0; j < 4; ++j) {
            int n = bn * TBN + wn + j * 16 + lrow;
            float bv = bias[n];
#pragma unroll
            for (int r = 0; r < 4; ++r) {
                float v = acc[i][j][r] + bv;
                if (ACT == 1) v = fmaxf(v, 0.f);
                else if (ACT == 2) v = tanhf(v);
                C[(size_t)(m0 + r) * N + n] = cvt_out<OutT>(v);
            }
        }
    }
}

// One wave per row: power-norm -> single-tap channel + noise -> LS h_est -> ZF.
__global__ __launch_bounds__(64) void channel_kernel(const float* __restrict__ s,
                                                     const float* __restrict__ h,
                                                     const float* __restrict__ noise,
                                                     float* __restrict__ xr_f,
                                                     bf16* __restrict__ xr_b) {
    const int b = blockIdx.x, lane = threadIdx.x;
    const float* srow = s + (size_t)b * 256;

    float ss = 0.f;
#pragma unroll
    for (int t = 0; t < 4; ++t) {
        float v = srow[lane + 64 * t];
        ss += v * v;
    }
#pragma unroll
    for (int off = 32; off; off >>= 1) ss += __shfl_xor(ss, off);
    const float inv = sqrtf(128.0f) / sqrtf(ss);

    const float hre = h[0], him = h[1];

    float yre[2], yim[2];
    float nre = 0.f, nim = 0.f, den = 0.f;
#pragma unroll
    for (int t = 0; t < 2; ++t) {
        int c = lane + 64 * t;
        float tr = srow[2 * c] * inv, ti = srow[2 * c + 1] * inv;
        float yr = hre * tr - him * ti + noise[(size_t)b * 256 + 2 * c];
        float yi = hre * ti + him * tr + noise[(size_t)b * 256 + 2 * c + 1];
        yre[t] = yr; yim[t] = yi;
        nre += yr * tr + yi * ti;
        nim += yi * tr - yr * ti;
        den += tr * tr + ti * ti;
    }
#pragma unroll
    for (int off = 32; off; off >>= 1) {
        nre += __shfl_xor(nre, off);
        nim += __shfl_xor(nim, off);
        den += __shfl_xor(den, off);
    }
    const float her = nre / den, hei = nim / den;
    const float d2 = her * her + hei * hei + 1e-12f;

#pragma unroll
    for (int t = 0; t < 2; ++t) {
        int c = lane + 64 * t;
        float xre = (yre[t] * her + yim[t] * hei) / d2;
        float xim = (yim[t] * her - yre[t] * hei) / d2;
        xr_f[(size_t)b * 256 + 2 * c] = xre;
        xr_f[(size_t)b * 256 + 2 * c + 1] = xim;
        xr_b[(size_t)b * 256 + 2 * c] = __float2bfloat16(xre);
        xr_b[(size_t)b * 256 + 2 * c + 1] = __float2bfloat16(xim);
    }
}

// One wave per row: h_inv = g2 @ w_rtn3^T + b_rtn3 (N=6), 3-tap complex FIR.
__global__ __launch_bounds__(64) void rtn_taps_conv(const bf16* __restrict__ g2,
                                                    const float* __restrict__ wr3,
                                                    const float* __restrict__ br3,
                                                    const float* __restrict__ xr_f,
                                                    bf16* __restrict__ xr2) {
    const int b = blockIdx.x, lane = threadIdx.x;
    const bf16* grow = g2 + (size_t)b * 1024;

    float acc[6] = {0.f, 0.f, 0.f, 0.f, 0.f, 0.f};
#pragma unroll
    for (int t = 0; t < 16; ++t) {
        int k = lane + 64 * t;
        float gv = __bfloat162float(grow[k]);
#pragma unroll
        for (int j = 0; j < 6; ++j) acc[j] += gv * wr3[j * 1024 + k];
    }
#pragma unroll
    for (int j = 0; j < 6; ++j)
#pragma unroll
        for (int off = 32; off; off >>= 1) acc[j] += __shfl_xor(acc[j], off);

    float tre[3], tim[3];
#pragma unroll
    for (int l = 0; l < 3; ++l) {
        tre[l] = acc[2 * l] + br3[2 * l];
        tim[l] = acc[2 * l + 1] + br3[2 * l + 1];
    }

    const float* xrow = xr_f + (size_t)b * 256;
#pragma unroll
    for (int t = 0; t < 2; ++t) {
        int c = lane + 64 * t;
        float ore = 0.f, oim = 0.f;
#pragma unroll
        for (int l = 0; l < 3; ++l) {
            int cc = c - l;
            if (cc >= 0) {
                float xre = xrow[2 * cc], xim = xrow[2 * cc + 1];
                ore += tre[l] * xre - tim[l] * xim;
                oim += tre[l] * xim + tim[l] * xre;
            }
        }
        xr2[(size_t)b * 256 + 2 * c] = __float2bfloat16(ore);
        xr2[(size_t)b * 256 + 2 * c + 1] = __float2bfloat16(oim);
    }
}

extern "C" void kernel_launch(void* const* d_in, const int* in_sizes, int n_in,
                              void* d_out, int out_size, void* d_ws, size_t ws_size,
                              hipStream_t stream) {
    constexpr int B = 8192, D_IN = 512, H1 = 4096, CH = 256, HR = 1024, H2 = 4096, DOUT = 512;

    const float* x   = (const float*)d_in[0];
    const float* w1  = (const float*)d_in[1];
    const float* b1  = (const float*)d_in[2];
    const float* w2  = (const float*)d_in[3];
    const float* b2  = (const float*)d_in[4];
    const float* wr1 = (const float*)d_in[5];
    const float* br1 = (const float*)d_in[6];
    const float* wr2 = (const float*)d_in[7];
    const float* br2 = (const float*)d_in[8];
    const float* wr3 = (const float*)d_in[9];
    const float* br3 = (const float*)d_in[10];
    const float* w3  = (const float*)d_in[11];
    const float* b3  = (const float*)d_in[12];
    const float* w4  = (const float*)d_in[13];
    const float* b4  = (const float*)d_in[14];
    const float* h   = (const float*)d_in[15];
    const float* noise = (const float*)d_in[16];

    // ---- workspace layout (bytes), peak 115.9 MB; liveness traced per launch ----
    char* ws = (char*)d_ws;
    bf16*  a    = (bf16*)(ws + 0);          // 64 MB: G1 out, G2 in; dead after G2
    float* sF   = (float*)(ws + 0);         // 8 MB: reduce(G2) out, channel in (a dead)
    bf16*  g1   = (bf16*)(ws + 0);          // 16 MB: G3 out (sF dead post-channel)
    bf16*  g2   = (bf16*)(ws + 16777216);   // 16 MB: G4 out, rtn in
    bf16*  tbuf = (bf16*)(ws + 0);          // 64 MB: G5 out (g1/g2 dead post-rtn)
    bf16*  w1B  = (bf16*)(ws + 67108864);   // 4 MB
    bf16*  w2B  = (bf16*)(ws + 71303168);   // 2 MB
    bf16*  wr1B = (bf16*)(ws + 73400320);   // 0.5 MB
    bf16*  wr2B = (bf16*)(ws + 73924608);   // 2 MB
    bf16*  w3B  = (bf16*)(ws + 76021760);   // 2 MB
    bf16*  w4B  = (bf16*)(ws + 78118912);   // 4 MB
    bf16*  xB   = (bf16*)(ws + 82313216);   // 8 MB: bf16(x), dead after G1
    bf16*  g2P  = (bf16*)(ws + 82313216);   // 4 x 4 MB: G2 bf16 partials (82..116 window dead at G2)
    float* xrF  = (float*)(ws + 99090432);  // 8 MB: channel out, rtn in
    bf16*  xrB  = (bf16*)(ws + 107479040);  // 4 MB: channel out, G3 in
    bf16*  xr2  = (bf16*)(ws + 111673344);  // 4 MB: rtn out, G5 in
    bf16*  g6P  = (bf16*)(ws + 82313216);   // 4 x 8 MB: G6 partials (xrF/xrB/xr2 dead at G6)

    dim3 blk(256);

    // ---- single fused fp32->bf16 convert ----
    CvtPack p;
    const float* srcs[7] = {x, w1, w2, wr1, wr2, w3, w4};
    bf16* dsts[7] = {xB, w1B, w2B, wr1B, wr2B, w3B, w4B};
    int ns[7] = {B * D_IN, H1 * D_IN, CH * H1, HR * CH, HR * HR, H2 * CH, DOUT * H2};
    int cum = 0;
    for (int i = 0; i < 7; ++i) { p.src[i] = srcs[i]; p.dst[i] = dsts[i]; cum += ns[i]; p.end[i] = cum; }
    cvt_all<<<(cum / 4 + 255) / 256, blk, 0, stream>>>(p);

    // ---- encoder ----
    // G1: 256x128 wide, nbm=32, nbn=32, grid 1024 x 512thr  [R9-proven]
    gemm_bt_wide<1, bf16><<<32 * 32, dim3(512), 0, stream>>>(
        xB, w1B, b1, a, B, H1, D_IN, 32);
    // G2: 128x64, split-K=4 (kc=1024), nbn=4, grid 1024 (4/CU) [R9 geometry],
    // bf16 partials (R10-proven accuracy; halves partial traffic)
    gemm_bt<0, bf16, 4, 2, 64, true><<<dim3(64 * 4, 4), blk, 0, stream>>>(
        a, w2B, nullptr, g2P, B, CH, H1, 4, H1 / 4);
    reduceK<4, 0, bf16, float><<<(B * CH / 4 + 255) / 256, blk, 0, stream>>>(
        g2P, b2, sF, (size_t)B * CH, CH - 1, B * CH / 4);
    // ---- channel + ZF (fp32) ----
    channel_kernel<<<B, 64, 0, stream>>>(sF, h, noise, xrF, xrB);
    // ---- RTN ----
    // G3: 128x64, nbm=64, nbn=16, grid 1024 [R9-proven]
    gemm_bt<2, bf16, 4, 2, 64, false><<<64 * 16, blk, 0, stream>>>(
        xrB, wr1B, br1, g1, B, HR, CH, 16, CH);
    // G4: direct 128x64, grid 1024 [R9-proven; R10 split regressed -> reverted]
    gemm_bt<2, bf16, 4, 2, 64, false><<<64 * 16, blk, 0, stream>>>(
        g1, wr2B, br2, g2, B, HR, HR, 16, HR);
    rtn_taps_conv<<<B, 64, 0, stream>>>(g2, wr3, br3, xrF, xr2);
    // ---- decoder ----
    // G5: 256x128 wide, nbm=32, nbn=32, grid 1024 x 512thr [R9-proven]
    gemm_bt_wide<1, bf16><<<32 * 32, dim3(512), 0, stream>>>(
        xr2, w3B, b3, tbuf, B, H2, CH, 32);
    // G6: 128x128, split-K=4 (kc=1024), nbn=4, grid (256,4)=1024, bf16 partials
    // [R10-measured 59 us vs R9's 66]
    gemm_bt<0, bf16, 4, 4, 64, true><<<dim3(64 * 4, 4), blk, 0, stream>>>(
        tbuf, w4B, nullptr, g6P, B, DOUT, H2, 4, H2 / 4);
    reduceK<4, 0, bf16, float><<<(B * DOUT / 4 + 255) / 256, blk, 0, stream>>>(
        g6P, b4, (float*)d_out, (size_t)B * DOUT, DOUT - 1, B * DOUT / 4);
}